// Round 1
// baseline (130.048 us; speedup 1.0000x reference)
//
#include <hip/hip_runtime.h>

// Problem constants (reference: B=8, N=16384, F=128, P=28)
#define BDIM  8
#define NDIM  16384
#define FDIM  128
#define PDIM  28
#define KPAD  896              // 28 p-steps * 32 padded q
#define MPTS  (BDIM * NDIM)    // 131072 points

typedef _Float16 half8  __attribute__((ext_vector_type(8)));
typedef float    floatx4 __attribute__((ext_vector_type(4)));

// ---------------------------------------------------------------------------
// Prep: IF [F][P][P] fp32  ->  IFt [F][KPAD] f16, k = p*32 + q, zero pad q>=28
// ---------------------------------------------------------------------------
__global__ __launch_bounds__(256) void prep_ift(const float* __restrict__ IF,
                                                _Float16* __restrict__ IFt) {
    int idx = blockIdx.x * 256 + threadIdx.x;     // 0 .. 128*896-1
    int f = idx / KPAD;
    int k = idx - f * KPAD;
    int p = k >> 5;
    int q = k & 31;
    float v = (q < PDIM) ? IF[f * (PDIM * PDIM) + p * PDIM + q] : 0.0f;
    IFt[idx] = (_Float16)v;
}

// ---------------------------------------------------------------------------
// Main: C[m,f] = sum_k W[m,k] * IFt[k,f],  W[m, p*32+q] = k0[m,p]*k1[m,q]
// Block: 128 points x 128 features, 4 waves (2x2), wave tile 64x64,
// mfma_f32_16x16x32_f16, K-loop = 28 steps of 32 (one p per step).
//
// B (IFt) is 229 KB total -> L1/L2-resident. Read B fragments DIRECTLY from
// global (one dwordx4 per lane per nt per step) instead of LDS-staging them:
// this removes both __syncthreads from the K-loop (no barrier vmcnt/lgkmcnt
// drain) and lets the compiler pipeline loads across MFMAs with counted
// waitcnts. k0s/k1s are per-point, built once in the prologue (one barrier).
// ---------------------------------------------------------------------------
__global__ __launch_bounds__(256, 4) void feats_kernel(
    const float* __restrict__ x,       // [MPTS][2]
    const float* __restrict__ sigma,   // [1] log lengthscale
    const _Float16* __restrict__ IFt,  // [FDIM][KPAD] f16
    float* __restrict__ out)           // [MPTS][FDIM]
{
    // k0: fp32, stride 29 floats  -> 16 lanes hit 16 distinct banks (29m mod 32)
    // k1: f16, stride 40 (80B) -> rows stay 16B-aligned; 2-way bank alias = free
    __shared__ float                  k0s[128 * 29];
    __shared__ __align__(16) _Float16 k1s[128 * 40];

    const int tid  = threadIdx.x;
    const int lane = tid & 63;
    const int wave = tid >> 6;
    const int wm   = wave & 1;          // wave row (points)
    const int wn   = wave >> 1;         // wave col (features)
    const int ln15 = lane & 15;
    const int quad = lane >> 4;

    const float ls    = __expf(sigma[0]);
    const float inv   = 0.5f / (ls * ls);
    const float gstep = 0.998f / 27.0f;

    // ---- prologue: build k0 (threads 0..127) and k1 (threads 128..255) ----
    {
        const int ptl = tid & 127;
        const int ptg = blockIdx.x * 128 + ptl;
        if (tid < 128) {
            const float x0 = x[2 * ptg + 0];
            #pragma unroll
            for (int p = 0; p < PDIM; p++) {
                float d = (0.001f + p * gstep) - x0;
                k0s[ptl * 29 + p] = __expf(-inv * d * d);
            }
        } else {
            const float x1 = x[2 * ptg + 1];
            #pragma unroll
            for (int q = 0; q < PDIM; q++) {
                float d = (0.001f + q * gstep) - x1;
                k1s[ptl * 40 + q] = (_Float16)__expf(-inv * d * d);
            }
            #pragma unroll
            for (int q = PDIM; q < 32; q++)
                k1s[ptl * 40 + q] = (_Float16)0.0f;   // zero pad (read by quad 3)
        }
    }
    __syncthreads();   // the ONLY barrier: k0s/k1s are read-only from here on

    // ---- hoisted k1 A-fragments: lane addresses are K-step invariant ----
    // A layout (16x16x32): A[m = lane&15][k = quad*8 + j]; within a K-step
    // k local = q, so lane needs k1[m][quad*8 .. +7] -> one ds_read_b128.
    half8 k1f[4];
    int   k0base[4];
    #pragma unroll
    for (int mt = 0; mt < 4; mt++) {
        const int mrow = wm * 64 + mt * 16 + ln15;
        k1f[mt]    = *(const half8*)&k1s[mrow * 40 + quad * 8];
        k0base[mt] = mrow * 29;
    }

    // ---- per-nt global base pointers for B fragments ----
    // B layout (16x16x32): B[k = quad*8+j][n = lane&15] <- IFt[nrow][kk*32 + quad*8]
    // 16 B per lane per load, 16B-aligned (rows are 1792 B).
    const _Float16* bptr[4];
    #pragma unroll
    for (int nt = 0; nt < 4; nt++) {
        const int nrow = wn * 64 + nt * 16 + ln15;
        bptr[nt] = IFt + nrow * KPAD + quad * 8;
    }

    floatx4 acc[4][4];
    #pragma unroll
    for (int mt = 0; mt < 4; mt++)
        #pragma unroll
        for (int nt = 0; nt < 4; nt++)
            acc[mt][nt] = (floatx4){0.0f, 0.0f, 0.0f, 0.0f};

    // ---- K-loop: no barriers. B fragments come straight from L1/L2. ----
    #pragma unroll 2
    for (int kk = 0; kk < PDIM; kk++) {             // kk == p
        half8 bf[4];
        #pragma unroll
        for (int nt = 0; nt < 4; nt++)
            bf[nt] = *(const half8*)&bptr[nt][kk * 32];

        #pragma unroll
        for (int mt = 0; mt < 4; mt++) {
            const float    k0v = k0s[k0base[mt] + kk];   // broadcast-ish read
            const _Float16 kh  = (_Float16)k0v;
            const half8    af  = k1f[mt] * kh;           // 4x v_pk_mul_f16
            #pragma unroll
            for (int nt = 0; nt < 4; nt++) {
                acc[mt][nt] = __builtin_amdgcn_mfma_f32_16x16x32_f16(
                    af, bf[nt], acc[mt][nt], 0, 0, 0);
            }
        }
    }

    // ---- epilogue: C/D layout col = lane&15 (feature), row = quad*4 + r ----
    #pragma unroll
    for (int mt = 0; mt < 4; mt++) {
        const int row0 = blockIdx.x * 128 + wm * 64 + mt * 16 + quad * 4;
        #pragma unroll
        for (int nt = 0; nt < 4; nt++) {
            const int col = wn * 64 + nt * 16 + ln15;
            float* op = out + (size_t)row0 * FDIM + col;
            #pragma unroll
            for (int r = 0; r < 4; r++)
                __builtin_nontemporal_store(acc[mt][nt][r], op + (size_t)r * FDIM);
        }
    }
}

// ---------------------------------------------------------------------------
extern "C" void kernel_launch(void* const* d_in, const int* in_sizes, int n_in,
                              void* d_out, int out_size, void* d_ws, size_t ws_size,
                              hipStream_t stream) {
    const float* x     = (const float*)d_in[0];   // [8,16384,2]
    const float* sigma = (const float*)d_in[1];   // [1]
    const float* IF    = (const float*)d_in[2];   // [128,28,28]
    float* out = (float*)d_out;                   // [8,16384,128] fp32

    // d_ws: IFt f16 [128][896] = 229376 bytes
    _Float16* IFt = (_Float16*)d_ws;

    prep_ift<<<(FDIM * KPAD) / 256, 256, 0, stream>>>(IF, IFt);          // 448 blocks
    feats_kernel<<<MPTS / 128, 256, 0, stream>>>(x, sigma, IFt, out);    // 1024 blocks
}

// Round 2
// 102.750 us; speedup vs baseline: 1.2657x; 1.2657x over previous
//
#include <hip/hip_runtime.h>
#include <stdint.h>

// Problem constants (reference: B=8, N=16384, F=128, P=28)
#define BDIM  8
#define NDIM  16384
#define FDIM  128
#define PDIM  28
#define MPTS  (BDIM * NDIM)    // 131072 points
#define SLICE 4096             // f16 per K-step slice: 128 f x 32 k

typedef _Float16 half8  __attribute__((ext_vector_type(8)));
typedef _Float16 half4  __attribute__((ext_vector_type(4)));
typedef float    floatx4 __attribute__((ext_vector_type(4)));

// ---------------------------------------------------------------------------
// Prep: IF [F][P][P] fp32 -> IFt_sw [28][128][4][8] f16.
// Layout per K-step kk: 128 rows (f) x 4 slots x 8 f16, where slot s holds
// ORIGINAL q-slot (s ^ ((f>>1)&3)) — the XOR bank-swizzle is baked into
// global so the main kernel's global_load_lds DMA can write LDS linearly
// (rule: swizzle both sides or neither; source permutation == read perm).
// q >= 28 zero-padded.
// ---------------------------------------------------------------------------
__global__ __launch_bounds__(256) void prep_ift(const float* __restrict__ IF,
                                                _Float16* __restrict__ IFt) {
    int idx = blockIdx.x * 256 + threadIdx.x;     // 0 .. 28*4096-1
    int kk  = idx >> 12;                          // p index
    int rem = idx & 4095;
    int f   = rem >> 5;
    int s   = (rem >> 3) & 3;
    int j   = idx & 7;
    int q   = ((s ^ ((f >> 1) & 3)) << 3) + j;    // original q
    float v = (q < PDIM) ? IF[f * (PDIM * PDIM) + kk * PDIM + q] : 0.0f;
    IFt[idx] = (_Float16)v;
}

// ---------------------------------------------------------------------------
// async global->LDS DMA, 16B per lane; LDS dest is wave-uniform base + lane*16
// ---------------------------------------------------------------------------
__device__ __forceinline__ void gload16(const _Float16* g, _Float16* l) {
    __builtin_amdgcn_global_load_lds(
        (const __attribute__((address_space(1))) void*)g,
        (__attribute__((address_space(3))) void*)l, 16, 0, 0);
}

// ---------------------------------------------------------------------------
// Main: C[m,f] = sum_k W[m,k] * IFt[k,f],  W[m, p*32+q] = k0[m,p]*k1[m,q]
// Block: 128 points x 128 features, 4 waves (2x2), wave tile 64x64,
// mfma_f32_16x16x32_f16, 28 K-steps of 32 (one p per step).
//
// Staging: global_load_lds dwordx4 (no VGPR roundtrip, no ds_write), double-
// buffered; ONE __syncthreads per K-step (its vmcnt(0)+lgkmcnt(0) drain is
// both the "stage done" and the "buffer free" proof). B fragment ds_read_b128
// uses the XOR-swizzled slot so any 8 consecutive lanes cover all 8 bank
// quads (conflict-free).
// ---------------------------------------------------------------------------
__global__ __launch_bounds__(256, 4) void feats_kernel(
    const float* __restrict__ x,       // [MPTS][2]
    const float* __restrict__ sigma,   // [1] log lengthscale
    const _Float16* __restrict__ IFt,  // [28][128][4][8] f16, pre-swizzled
    float* __restrict__ out)           // [MPTS][FDIM]
{
    __shared__ __align__(16) _Float16 bs[2][SLICE];   // 2 x 8KB B slices
    __shared__ __align__(16) _Float16 k1s[128 * 40];  // stride 40: 80B rows
    __shared__ __align__(16) _Float16 k0t[PDIM * 128];// [p][wm][ln15][mt] f16

    const int tid  = threadIdx.x;
    const int lane = tid & 63;
    const int wave = tid >> 6;
    const int wm   = wave & 1;          // wave row (points)
    const int wn   = wave >> 1;         // wave col (features)
    const int ln15 = lane & 15;
    const int quad = lane >> 4;

    const _Float16* gsrc = IFt + tid * 8;   // per-thread DMA source base

    // ---- stage K-step 0 into bs[0]; DMA overlaps the exp prologue ----
    gload16(gsrc,        &bs[0][tid * 8]);
    gload16(gsrc + 2048, &bs[0][tid * 8 + 2048]);

    const float ls    = __expf(sigma[0]);
    const float inv   = 0.5f / (ls * ls);
    const float gstep = 0.998f / 27.0f;

    // ---- prologue: k0 (threads 0..127, transposed f16) / k1 (128..255) ----
    {
        const int ptl = tid & 127;
        const int ptg = blockIdx.x * 128 + ptl;
        if (tid < 128) {
            const float x0 = x[2 * ptg + 0];
            // point m = ptl: wm = m>>6, mt = (m>>4)&3, l15 = m&15
            const int base = (ptl >> 6) * 64 + (ptl & 15) * 4 + ((ptl >> 4) & 3);
            #pragma unroll
            for (int p = 0; p < PDIM; p++) {
                float d = (0.001f + p * gstep) - x0;
                k0t[p * 128 + base] = (_Float16)__expf(-inv * d * d);
            }
        } else {
            const float x1 = x[2 * ptg + 1];
            #pragma unroll
            for (int q = 0; q < PDIM; q++) {
                float d = (0.001f + q * gstep) - x1;
                k1s[ptl * 40 + q] = (_Float16)__expf(-inv * d * d);
            }
            #pragma unroll
            for (int q = PDIM; q < 32; q++)
                k1s[ptl * 40 + q] = (_Float16)0.0f;   // zero pad (quad 3 reads)
        }
    }
    __syncthreads();   // k0t/k1s ready; bs[0] DMA drained (vmcnt0 in barrier)

    // ---- hoisted K-invariant fragments / offsets ----
    // A layout (16x16x32): A[m = lane&15][k = quad*8 + j]; k local = q.
    half8 k1f[4];
    #pragma unroll
    for (int mt = 0; mt < 4; mt++) {
        const int mrow = wm * 64 + mt * 16 + ln15;
        k1f[mt] = *(const half8*)&k1s[mrow * 40 + quad * 8];
    }
    // B fragment: B[k = quad*8+j][n = f] at swizzled slot (quad ^ ((f>>1)&3))
    int bfo[4];
    #pragma unroll
    for (int nt = 0; nt < 4; nt++) {
        const int f = wn * 64 + nt * 16 + ln15;
        bfo[nt] = f * 32 + ((quad ^ ((f >> 1) & 3)) << 3);
    }
    const int k0o = wm * 64 + ln15 * 4;  // one b64 -> all 4 mt values, bcast

    floatx4 acc[4][4];
    #pragma unroll
    for (int mt = 0; mt < 4; mt++)
        #pragma unroll
        for (int nt = 0; nt < 4; nt++)
            acc[mt][nt] = (floatx4){0.0f, 0.0f, 0.0f, 0.0f};

#define MFMA_STEP(KK, BUF)                                                   \
    do {                                                                     \
        half8 bf[4];                                                         \
        _Pragma("unroll")                                                    \
        for (int nt = 0; nt < 4; nt++)                                       \
            bf[nt] = *(const half8*)&bs[BUF][bfo[nt]];                       \
        const half4 k0v = *(const half4*)&k0t[(KK) * 128 + k0o];             \
        _Pragma("unroll")                                                    \
        for (int mt = 0; mt < 4; mt++) {                                     \
            const half8 af = k1f[mt] * k0v[mt];                              \
            _Pragma("unroll")                                                \
            for (int nt = 0; nt < 4; nt++)                                   \
                acc[mt][nt] = __builtin_amdgcn_mfma_f32_16x16x32_f16(        \
                    af, bf[nt], acc[mt][nt], 0, 0, 0);                       \
        }                                                                    \
    } while (0)

    // ---- K-loop: 1 barrier per step, DMA always into the other buffer ----
    #pragma unroll 1
    for (int kk = 0; kk < PDIM; kk += 2) {
        // even step: compute bs[0], stage kk+1 -> bs[1]
        gload16(gsrc + (kk + 1) * SLICE,        &bs[1][tid * 8]);
        gload16(gsrc + (kk + 1) * SLICE + 2048, &bs[1][tid * 8 + 2048]);
        MFMA_STEP(kk, 0);
        __syncthreads();   // bs[1] ready; bs[0] reads drained

        // odd step: compute bs[1], stage kk+2 -> bs[0]
        if (kk + 2 < PDIM) {
            gload16(gsrc + (kk + 2) * SLICE,        &bs[0][tid * 8]);
            gload16(gsrc + (kk + 2) * SLICE + 2048, &bs[0][tid * 8 + 2048]);
        }
        MFMA_STEP(kk + 1, 1);
        if (kk + 2 < PDIM) __syncthreads();   // bs[0] ready; bs[1] drained
    }
#undef MFMA_STEP

    // ---- epilogue: C/D layout col = lane&15 (feature), row = quad*4 + r ----
    #pragma unroll
    for (int mt = 0; mt < 4; mt++) {
        const int row0 = blockIdx.x * 128 + wm * 64 + mt * 16 + quad * 4;
        #pragma unroll
        for (int nt = 0; nt < 4; nt++) {
            const int col = wn * 64 + nt * 16 + ln15;
            float* op = out + (size_t)row0 * FDIM + col;
            #pragma unroll
            for (int r = 0; r < 4; r++)
                __builtin_nontemporal_store(acc[mt][nt][r], op + (size_t)r * FDIM);
        }
    }
}

// ---------------------------------------------------------------------------
extern "C" void kernel_launch(void* const* d_in, const int* in_sizes, int n_in,
                              void* d_out, int out_size, void* d_ws, size_t ws_size,
                              hipStream_t stream) {
    const float* x     = (const float*)d_in[0];   // [8,16384,2]
    const float* sigma = (const float*)d_in[1];   // [1]
    const float* IF    = (const float*)d_in[2];   // [128,28,28]
    float* out = (float*)d_out;                   // [8,16384,128] fp32

    // d_ws: IFt_sw f16 [28][128][4][8] = 229376 bytes
    _Float16* IFt = (_Float16*)d_ws;

    prep_ift<<<(PDIM * SLICE) / 256, 256, 0, stream>>>(IF, IFt);         // 448 blocks
    feats_kernel<<<MPTS / 128, 256, 0, stream>>>(x, sigma, IFt, out);    // 1024 blocks
}

// Round 3
// 101.659 us; speedup vs baseline: 1.2793x; 1.0107x over previous
//
#include <hip/hip_runtime.h>
#include <stdint.h>

// Problem constants (reference: B=8, N=16384, F=128, P=28)
#define BDIM   8
#define NDIM   16384
#define FDIM   128
#define PDIM   28
#define MPTS   (BDIM * NDIM)     // 131072 points
#define SLICE  4096              // f16 per kk slab in global: 128 f x 32 q
#define HSLICE 2048              // f16 per kk half-slab in LDS: 64 f x 32 q
#define TPTS   256               // points per M-tile
#define TILES  2                 // M-tiles per block
#define CPTS   (TPTS * TILES)    // 512 points per block

typedef _Float16 half8  __attribute__((ext_vector_type(8)));
typedef _Float16 half4  __attribute__((ext_vector_type(4)));
typedef float    floatx4 __attribute__((ext_vector_type(4)));

// ---------------------------------------------------------------------------
// Prep: IF [F][P][P] fp32 -> IFt_sw [28][128][4][8] f16.
// Slot s of row f holds ORIGINAL q-slot (s ^ ((f>>1)&3)) — XOR bank-swizzle
// baked into global so the main kernel's global_load_lds DMA writes LDS
// linearly (swizzle both sides or neither). q >= 28 zero-padded.
// ---------------------------------------------------------------------------
__global__ __launch_bounds__(256) void prep_ift(const float* __restrict__ IF,
                                                _Float16* __restrict__ IFt) {
    int idx = blockIdx.x * 256 + threadIdx.x;     // 0 .. 28*4096-1
    int kk  = idx >> 12;                          // p index
    int rem = idx & 4095;
    int f   = rem >> 5;
    int s   = (rem >> 3) & 3;
    int j   = idx & 7;
    int q   = ((s ^ ((f >> 1) & 3)) << 3) + j;    // original q
    float v = (q < PDIM) ? IF[f * (PDIM * PDIM) + kk * PDIM + q] : 0.0f;
    IFt[idx] = (_Float16)v;
}

// ---------------------------------------------------------------------------
// async global->LDS DMA, 16B per lane; LDS dest is wave-uniform base + lane*16
// ---------------------------------------------------------------------------
__device__ __forceinline__ void gload16(const _Float16* g, _Float16* l) {
    __builtin_amdgcn_global_load_lds(
        (const __attribute__((address_space(1))) void*)g,
        (__attribute__((address_space(3))) void*)l, 16, 0, 0);
}

// ---------------------------------------------------------------------------
// Main: C[m,f] = sum_k W[m,k] * IFt[k,f],  W[m, p*32+q] = k0[m,p]*k1[m,q]
//
// NEW STRUCTURE: each block owns ONE 64-feature half of B (114.7 KB), stages
// it into LDS ONCE, then computes 2 M-tiles of 256 points against it with
// ZERO barriers inside the K-loop (B is read-only resident; k0/k1 are per-
// tile with 2 barriers per tile). 8 waves (4m x 2n), wave tile 64 pts x 32 f,
// mfma_f32_16x16x32_f16, 28 K-steps, 8 MFMA / wave / step.
// ---------------------------------------------------------------------------
__global__ __launch_bounds__(512, 1) void feats_kernel(
    const float* __restrict__ x,       // [MPTS][2]
    const float* __restrict__ sigma,   // [1] log lengthscale
    const _Float16* __restrict__ IFt,  // [28][128][4][8] f16, pre-swizzled
    float* __restrict__ out)           // [MPTS][FDIM]
{
    __shared__ __align__(16) _Float16 bs [PDIM * HSLICE];  // 114688 B: B half
    __shared__ __align__(16) _Float16 k1s[TPTS * 40];      //  20480 B (80B rows)
    __shared__ __align__(16) _Float16 k0t[PDIM * TPTS];    //  14336 B [p][m']

    const int tid   = threadIdx.x;
    const int lane  = tid & 63;
    const int wave  = tid >> 6;          // 0..7
    const int wm    = wave >> 1;         // 0..3: point-row of wave
    const int wn    = wave & 1;          // 0..1: feature-col of wave
    const int ln15  = lane & 15;
    const int quad  = lane >> 4;
    const int chunk = blockIdx.x >> 1;   // 512-point chunk id
    const int h     = blockIdx.x & 1;    // feature half

    // ---- stage the whole B-half ONCE: 28 slabs x 4KB, waves 0..3 ----
    // slab kk (global): IFt + kk*SLICE + h*HSLICE, 2048 f16 = 256 lanes x 16B
    if (tid < 256) {
        const _Float16* g = IFt + h * HSLICE + tid * 8;
        #pragma unroll
        for (int kk = 0; kk < PDIM; kk++)
            gload16(g + kk * SLICE, &bs[kk * HSLICE + tid * 8]);
    }

    const float ls    = __expf(sigma[0]);
    const float inv   = 0.5f / (ls * ls);
    const float gstep = 0.998f / 27.0f;

    // ---- K-invariant offsets ----
    // B fragment: B[k = quad*8+j][f] at swizzled slot (quad ^ ((fl>>1)&3)).
    // (f = h*64 + fl; bit6 doesn't touch bits 1..2, so swz from fl is exact.)
    int bfo[2];
    #pragma unroll
    for (int nt = 0; nt < 2; nt++) {
        const int fl = wn * 32 + nt * 16 + ln15;        // 0..63
        bfo[nt] = fl * 32 + ((quad ^ ((fl >> 1) & 3)) << 3);
    }
    const int k0o  = wm * 64 + ln15 * 4;   // one b64 -> k0 for mt=0..3
    const int k1ro = wm * 64 + ln15;       // + mt*16, row in k1s

    #pragma unroll 1
    for (int tile = 0; tile < TILES; tile++) {
        // ---- per-tile prologue: k0 (threads 0..255) / k1 (256..511) ----
        {
            const int ptl = tid & 255;
            const int ptg = chunk * CPTS + tile * TPTS + ptl;
            if (tid < 256) {
                const float x0 = x[2 * ptg + 0];
                // m = ptl: k0t index [p][ (m>>6)*64 + (m&15)*4 + ((m>>4)&3) ]
                const int base = (ptl >> 6) * 64 + (ptl & 15) * 4 + ((ptl >> 4) & 3);
                #pragma unroll
                for (int p = 0; p < PDIM; p++) {
                    float d = (0.001f + p * gstep) - x0;
                    k0t[p * TPTS + base] = (_Float16)__expf(-inv * d * d);
                }
            } else {
                const float x1 = x[2 * ptg + 1];
                #pragma unroll
                for (int q = 0; q < PDIM; q++) {
                    float d = (0.001f + q * gstep) - x1;
                    k1s[ptl * 40 + q] = (_Float16)__expf(-inv * d * d);
                }
                #pragma unroll
                for (int q = PDIM; q < 32; q++)
                    k1s[ptl * 40 + q] = (_Float16)0.0f;   // zero pad (quad 3)
            }
        }
        __syncthreads();   // k0t/k1s ready; (tile 0: also drains B DMA)

        // ---- hoisted k1 A-fragments (K-invariant within tile) ----
        // A layout (16x16x32): A[m = lane&15][k = quad*8 + j], k local = q.
        half8 k1f[4];
        #pragma unroll
        for (int mt = 0; mt < 4; mt++)
            k1f[mt] = *(const half8*)&k1s[(k1ro + mt * 16) * 40 + quad * 8];

        floatx4 acc[4][2];
        #pragma unroll
        for (int mt = 0; mt < 4; mt++)
            #pragma unroll
            for (int nt = 0; nt < 2; nt++)
                acc[mt][nt] = (floatx4){0.0f, 0.0f, 0.0f, 0.0f};

        // ---- K-loop: NO barriers, pure LDS-read + MFMA ----
        #pragma unroll 4
        for (int kk = 0; kk < PDIM; kk++) {
            half8 bf[2];
            #pragma unroll
            for (int nt = 0; nt < 2; nt++)
                bf[nt] = *(const half8*)&bs[kk * HSLICE + bfo[nt]];
            const half4 k0v = *(const half4*)&k0t[kk * TPTS + k0o];
            #pragma unroll
            for (int mt = 0; mt < 4; mt++) {
                const half8 af = k1f[mt] * k0v[mt];     // 4x v_pk_mul_f16
                #pragma unroll
                for (int nt = 0; nt < 2; nt++)
                    acc[mt][nt] = __builtin_amdgcn_mfma_f32_16x16x32_f16(
                        af, bf[nt], acc[mt][nt], 0, 0, 0);
            }
        }

        // ---- epilogue: C/D col = lane&15 (feature), row = quad*4 + r ----
        #pragma unroll
        for (int mt = 0; mt < 4; mt++) {
            const int row0 = chunk * CPTS + tile * TPTS + wm * 64 + mt * 16 + quad * 4;
            #pragma unroll
            for (int nt = 0; nt < 2; nt++) {
                const int col = h * 64 + wn * 32 + nt * 16 + ln15;
                float* op = out + (size_t)row0 * FDIM + col;
                #pragma unroll
                for (int r = 0; r < 4; r++)
                    __builtin_nontemporal_store(acc[mt][nt][r], op + (size_t)r * FDIM);
            }
        }

        if (tile + 1 < TILES)
            __syncthreads();   // k0t/k1s reads done before next tile overwrites
    }
}

// ---------------------------------------------------------------------------
extern "C" void kernel_launch(void* const* d_in, const int* in_sizes, int n_in,
                              void* d_out, int out_size, void* d_ws, size_t ws_size,
                              hipStream_t stream) {
    const float* x     = (const float*)d_in[0];   // [8,16384,2]
    const float* sigma = (const float*)d_in[1];   // [1]
    const float* IF    = (const float*)d_in[2];   // [128,28,28]
    float* out = (float*)d_out;                   // [8,16384,128] fp32

    // d_ws: IFt_sw f16 [28][128][4][8] = 229376 bytes
    _Float16* IFt = (_Float16*)d_ws;

    prep_ift<<<(PDIM * SLICE) / 256, 256, 0, stream>>>(IF, IFt);         // 448 blocks
    // 256 chunks of 512 points x 2 feature-halves = 512 blocks, 1 per CU
    feats_kernel<<<(MPTS / CPTS) * 2, 512, 0, stream>>>(x, sigma, IFt, out);
}